// Round 15
// baseline (255.564 us; speedup 1.0000x reference)
//
#include <hip/hip_runtime.h>

// y[b, n*DOUT+o] = sum_i x[b,n,i] * W[n,i,o] + bias[n,o]
// B=2048, N=64, DIN=512, DOUT=512, fp32 in/out, bf16 MFMA (fp32 accum).
// R12: 256x256 tile, BK=64, 8 K-tiles, 512 thr (8 waves 2x4, wave 128x64).
// ONE barrier per K-tile (64 MFMA/wave between barriers). Counted vmcnt:
// queue [B4(t), A8(t+1), B4(t+1)] -> vmcnt(12) drains B(t) only; vmcnt(4)
// after compute drains A; B(t+1) flies a whole tile. W pre-pass emits a
// K-tiled PRE-SWIZZLED layout so B DMA is contiguous 1KB/inst.

#define NN 64
#define DIN 512
#define DOUT 512
#define BM 256
#define BN 256
#define BK 64
#define NTILES 8                  // K-tiles = DIN/BK
#define ROWSTRIDE (NN * DIN)
#define OUTSTRIDE (NN * DOUT)
#define PANEL 16384               // shorts per (node,ntile,kt) B panel: 256*64

typedef __bf16 bf16x8 __attribute__((ext_vector_type(8)));
typedef float f32x4 __attribute__((ext_vector_type(4)));

__device__ __forceinline__ unsigned short f2bf(float f) {
    return __builtin_bit_cast(unsigned short, (__bf16)f);  // RNE
}
__device__ __forceinline__ unsigned int f2bf2(float a, float b) {
    return (unsigned int)f2bf(a) | ((unsigned int)f2bf(b) << 16);
}

typedef const __attribute__((address_space(1))) unsigned int* gas1_t;
typedef __attribute__((address_space(3))) unsigned int* las3_t;
__device__ __forceinline__ void gload_lds16(const void* g, void* l) {
    __builtin_amdgcn_global_load_lds((gas1_t)g, (las3_t)l, 16, 0, 0);
}

#define WAITV(n)  asm volatile("s_waitcnt vmcnt(" #n ")" ::: "memory")
#define WAITLGKM  asm volatile("s_waitcnt lgkmcnt(0)" ::: "memory")

// ---- pre-pass: Wt2 K-tiled + pre-swizzled ----
// Wt2[((n*2+nt)*8+kt)*16384 + col*64 + (slot^(col&7))*8 + e] = bf16(W[n][i][o])
// where nt=o>>8, col=o&255, kt=i>>6, slot=(i>>3)&7, e=i&7.
__global__ void wt_transpose_kernel(const float* __restrict__ W,
                                    unsigned short* __restrict__ Wt2) {
    __shared__ float tile[32][33];
    const int n  = blockIdx.z;
    const int i0 = blockIdx.x * 32;
    const int o0 = blockIdx.y * 32;
    const float* Wn = W + (size_t)n * DIN * DOUT;
    const int tx = threadIdx.x, ty = threadIdx.y;
#pragma unroll
    for (int q = 0; q < 4; ++q)
        tile[ty + q * 8][tx] = Wn[(size_t)(i0 + ty + q * 8) * DOUT + (o0 + tx)];
    __syncthreads();
#pragma unroll
    for (int q = 0; q < 4; ++q) {
        const int o = o0 + ty + q * 8;
        const int i = i0 + tx;
        const int nt = o >> 8, col = o & 255;
        const int kt = i >> 6, slot = (i >> 3) & 7, e = i & 7;
        const size_t idx = ((size_t)((n * 2 + nt) * 8 + kt)) * PANEL +
                           col * 64 + ((slot ^ (col & 7)) * 8) + e;
        Wt2[idx] = f2bf(tile[tx][ty + q * 8]);
    }
}

// ---- main GEMM ----
__global__ __launch_bounds__(512, 2) void node_gemm_kernel(
    const float* __restrict__ X, const unsigned short* __restrict__ Wt2,
    const float* __restrict__ Bias, float* __restrict__ Out) {
    __shared__ unsigned short As[2][BM * 64];   // 2 x 32 KB, [row][slot^(row&7)]
    __shared__ unsigned short Bs[2][BN * 64];   // 2 x 32 KB, pre-swizzled via source

    // grid 1024 = 64 nodes x 8 mtiles x 2 ntiles; node -> XCD affinity
    const int bid  = blockIdx.x;
    const int xcd  = bid & 7;
    const int seq  = bid >> 3;             // 0..127
    const int node = (seq >> 4) * 8 + xcd; // 0..63
    const int rem  = seq & 15;
    const int mtile = rem >> 1;
    const int ntile = rem & 1;
    const int brow = mtile * BM;

    const int tid  = threadIdx.x;
    const int lane = tid & 63;
    const int w    = tid >> 6;        // 0..7
    const int wm   = w >> 2;          // 0..1: rows wm*128..
    const int wn   = w & 3;           // 0..3: cols wn*64..

    const float* Xb = X + (size_t)brow * ROWSTRIDE + node * DIN;
    const unsigned short* Wb2 = Wt2 + (size_t)((node * 2 + ntile) * 8) * PANEL;

    // A staging: thread t -> row t>>1 (0..255), half t&1 (floats 32h..32h+31)
    const int a_row  = tid >> 1;
    const int a_half = tid & 1;
    const float* a_src = Xb + (size_t)a_row * ROWSTRIDE + a_half * 32;
    const int a_base = a_row * 64;         // shorts
    const int a_rx   = a_row & 7;

    // B DMA: wave w handles chunks c = w*4+q (q=0..3), 1KB each, contiguous
    // fragment offsets
    const int frow = lane & 15;
    const int akk  = lane >> 4;            // 0..3
    const int cx   = frow & 7;

    f32x4 acc[8][4] = {};
    float4 av[8];                          // A stage regs (32 VGPR)

    auto loadA = [&](int kt) {
        const float* p = a_src + kt * BK;
#pragma unroll
        for (int i = 0; i < 8; ++i)
            av[i] = *reinterpret_cast<const float4*>(p + i * 4);
    };
    auto storeA = [&](int buf) {
#pragma unroll
        for (int j = 0; j < 4; ++j) {
            uint4 pk;
            pk.x = f2bf2(av[2 * j].x, av[2 * j].y);
            pk.y = f2bf2(av[2 * j].z, av[2 * j].w);
            pk.z = f2bf2(av[2 * j + 1].x, av[2 * j + 1].y);
            pk.w = f2bf2(av[2 * j + 1].z, av[2 * j + 1].w);
            *reinterpret_cast<uint4*>(
                &As[buf][a_base + ((a_half * 4 + j) ^ a_rx) * 8]) = pk;
        }
    };
    auto stageB = [&](int buf, int kt) {
#pragma unroll
        for (int q = 0; q < 4; ++q) {
            const int c = w * 4 + q;
            gload_lds16(Wb2 + (size_t)kt * PANEL + c * 512 + lane * 8,
                        &Bs[buf][c * 512]);
        }
    };
    auto compute = [&](int buf) {
#pragma unroll
        for (int kk = 0; kk < 2; ++kk) {
            const int ks = ((kk * 4 + akk) ^ cx) * 8;
            bf16x8 bq[4];
#pragma unroll
            for (int n = 0; n < 4; ++n)
                bq[n] = *reinterpret_cast<const bf16x8*>(
                    &Bs[buf][(wn * 64 + n * 16 + frow) * 64 + ks]);
#pragma unroll
            for (int mh = 0; mh < 2; ++mh) {
                bf16x8 af[4];
#pragma unroll
                for (int m = 0; m < 4; ++m)
                    af[m] = *reinterpret_cast<const bf16x8*>(
                        &As[buf][(wm * 128 + (mh * 4 + m) * 16 + frow) * 64 + ks]);
                __builtin_amdgcn_s_setprio(1);
#pragma unroll
                for (int m = 0; m < 4; ++m)
#pragma unroll
                    for (int n = 0; n < 4; ++n)
                        acc[mh * 4 + m][n] = __builtin_amdgcn_mfma_f32_16x16x32_bf16(
                            af[m], bq[n], acc[mh * 4 + m][n], 0, 0, 0);
                __builtin_amdgcn_s_setprio(0);
            }
        }
    };

    // ---- prologue: A(0) -> LDS buf0 (one-time drain), B(0) DMA in flight
    loadA(0);
    WAITV(0);
    storeA(0);
    stageB(0, 0);

    // ---- main loop: one barrier per K-tile; staging issued AFTER the barrier
    // (all waves past tile t-1's reads -> WAR-safe), counted vmcnt never 0.
#pragma unroll
    for (int t = 0; t < NTILES; ++t) {
        const int buf = t & 1;
        WAITLGKM;                           // my ds_writes/reads retired
        __builtin_amdgcn_s_barrier();       // all waves done with buf^1
        __builtin_amdgcn_sched_barrier(0);
        if (t < NTILES - 1) {
            loadA(t + 1);                   // queue: B4(t), A8
            stageB(buf ^ 1, t + 1);         // queue: B4(t), A8, B4(t+1)
            WAITV(12);                      // drain B(t); 12 stay in flight
        } else {
            WAITV(0);                       // tail: only B(7) outstanding
        }
        __builtin_amdgcn_sched_barrier(0);
        compute(buf);
        if (t < NTILES - 1) {
            WAITV(4);                       // drain A(t+1); B(t+1) keeps flying
            __builtin_amdgcn_sched_barrier(0);
            storeA(buf ^ 1);
        }
    }

    // ---- epilogue: D mapping col = lane&15, row = (lane>>4)*4 + j
    const float* bn = Bias + node * DOUT + ntile * 256;
    float* outb = Out + (size_t)brow * OUTSTRIDE + node * DOUT + ntile * 256;
#pragma unroll
    for (int n = 0; n < 4; ++n) {
        const int col = wn * 64 + n * 16 + frow;
        const float bias = bn[col];
#pragma unroll
        for (int m = 0; m < 8; ++m) {
            const int r0 = wm * 128 + m * 16 + akk * 4;
#pragma unroll
            for (int j = 0; j < 4; ++j)
                outb[(size_t)(r0 + j) * OUTSTRIDE + col] = acc[m][n][j] + bias;
        }
    }
}

extern "C" void kernel_launch(void* const* d_in, const int* in_sizes, int n_in,
                              void* d_out, int out_size, void* d_ws, size_t ws_size,
                              hipStream_t stream) {
    const float* x = (const float*)d_in[0];      // [2048, 64, 512]
    const float* W = (const float*)d_in[1];      // [64, 512, 512]
    const float* b = (const float*)d_in[2];      // [64, 512]
    float* out = (float*)d_out;                  // [2048, 64*512]
    unsigned short* Wt2 = (unsigned short*)d_ws; // bf16, 33.5 MB, K-tiled+swizzled

    wt_transpose_kernel<<<dim3(DIN / 32, DOUT / 32, NN), dim3(32, 8), 0, stream>>>(W, Wt2);
    node_gemm_kernel<<<dim3(1024), dim3(512), 0, stream>>>(x, Wt2, b, out);
}

// Round 16
// 252.943 us; speedup vs baseline: 1.0104x; 1.0104x over previous
//
#include <hip/hip_runtime.h>

// y[b, n*DOUT+o] = sum_i x[b,n,i] * W[n,i,o] + bias[n,o]
// B=2048, N=64, DIN=512, DOUT=512, fp32 in/out, bf16 MFMA (fp32 accum).
// R12: 256x256 tile, BK=64, 8 K-tiles, 512 thr (8 waves 2x4, wave 128x64).
// ONE barrier per K-tile (64 MFMA/wave between barriers). Counted vmcnt:
// queue [B4(t), A8(t+1), B4(t+1)] -> vmcnt(12) drains B(t) only; vmcnt(4)
// after compute drains A; B(t+1) flies a whole tile. W pre-pass emits a
// K-tiled PRE-SWIZZLED layout so B DMA is contiguous 1KB/inst.

#define NN 64
#define DIN 512
#define DOUT 512
#define BM 256
#define BN 256
#define BK 64
#define NTILES 8                  // K-tiles = DIN/BK
#define ROWSTRIDE (NN * DIN)
#define OUTSTRIDE (NN * DOUT)
#define PANEL 16384               // shorts per (node,ntile,kt) B panel: 256*64

typedef __bf16 bf16x8 __attribute__((ext_vector_type(8)));
typedef float f32x4 __attribute__((ext_vector_type(4)));

__device__ __forceinline__ unsigned short f2bf(float f) {
    return __builtin_bit_cast(unsigned short, (__bf16)f);  // RNE
}
__device__ __forceinline__ unsigned int f2bf2(float a, float b) {
    return (unsigned int)f2bf(a) | ((unsigned int)f2bf(b) << 16);
}

typedef const __attribute__((address_space(1))) unsigned int* gas1_t;
typedef __attribute__((address_space(3))) unsigned int* las3_t;
__device__ __forceinline__ void gload_lds16(const void* g, void* l) {
    __builtin_amdgcn_global_load_lds((gas1_t)g, (las3_t)l, 16, 0, 0);
}

#define WAITV(n)  asm volatile("s_waitcnt vmcnt(" #n ")" ::: "memory")
#define WAITLGKM  asm volatile("s_waitcnt lgkmcnt(0)" ::: "memory")

// ---- pre-pass: Wt2 K-tiled + pre-swizzled ----
// Wt2[((n*2+nt)*8+kt)*16384 + col*64 + (slot^(col&7))*8 + e] = bf16(W[n][i][o])
// where nt=o>>8, col=o&255, kt=i>>6, slot=(i>>3)&7, e=i&7.
__global__ void wt_transpose_kernel(const float* __restrict__ W,
                                    unsigned short* __restrict__ Wt2) {
    __shared__ float tile[32][33];
    const int n  = blockIdx.z;
    const int i0 = blockIdx.x * 32;
    const int o0 = blockIdx.y * 32;
    const float* Wn = W + (size_t)n * DIN * DOUT;
    const int tx = threadIdx.x, ty = threadIdx.y;
#pragma unroll
    for (int q = 0; q < 4; ++q)
        tile[ty + q * 8][tx] = Wn[(size_t)(i0 + ty + q * 8) * DOUT + (o0 + tx)];
    __syncthreads();
#pragma unroll
    for (int q = 0; q < 4; ++q) {
        const int o = o0 + ty + q * 8;
        const int i = i0 + tx;
        const int nt = o >> 8, col = o & 255;
        const int kt = i >> 6, slot = (i >> 3) & 7, e = i & 7;
        const size_t idx = ((size_t)((n * 2 + nt) * 8 + kt)) * PANEL +
                           col * 64 + ((slot ^ (col & 7)) * 8) + e;
        Wt2[idx] = f2bf(tile[tx][ty + q * 8]);
    }
}

// ---- main GEMM ----
__global__ __launch_bounds__(512, 2) void node_gemm_kernel(
    const float* __restrict__ X, const unsigned short* __restrict__ Wt2,
    const float* __restrict__ Bias, float* __restrict__ Out) {
    __shared__ unsigned short As[2][BM * 64];   // 2 x 32 KB, [row][slot^(row&7)]
    __shared__ unsigned short Bs[2][BN * 64];   // 2 x 32 KB, pre-swizzled via source

    // grid 1024 = 64 nodes x 8 mtiles x 2 ntiles; node -> XCD affinity
    const int bid  = blockIdx.x;
    const int xcd  = bid & 7;
    const int seq  = bid >> 3;             // 0..127
    const int node = (seq >> 4) * 8 + xcd; // 0..63
    const int rem  = seq & 15;
    const int mtile = rem >> 1;
    const int ntile = rem & 1;
    const int brow = mtile * BM;

    const int tid  = threadIdx.x;
    const int lane = tid & 63;
    const int w    = tid >> 6;        // 0..7
    const int wm   = w >> 2;          // 0..1: rows wm*128..
    const int wn   = w & 3;           // 0..3: cols wn*64..

    const float* Xb = X + (size_t)brow * ROWSTRIDE + node * DIN;
    const unsigned short* Wb2 = Wt2 + (size_t)((node * 2 + ntile) * 8) * PANEL;

    // A staging: thread t -> row t>>1 (0..255), half t&1 (floats 32h..32h+31)
    const int a_row  = tid >> 1;
    const int a_half = tid & 1;
    const float* a_src = Xb + (size_t)a_row * ROWSTRIDE + a_half * 32;
    const int a_base = a_row * 64;         // shorts
    const int a_rx   = a_row & 7;

    // B DMA: wave w handles chunks c = w*4+q (q=0..3), 1KB each, contiguous
    // fragment offsets
    const int frow = lane & 15;
    const int akk  = lane >> 4;            // 0..3
    const int cx   = frow & 7;

    f32x4 acc[8][4] = {};
    float4 av[8];                          // A stage regs (32 VGPR)

    auto loadA = [&](int kt) {
        const float* p = a_src + kt * BK;
#pragma unroll
        for (int i = 0; i < 8; ++i)
            av[i] = *reinterpret_cast<const float4*>(p + i * 4);
    };
    auto storeA = [&](int buf) {
#pragma unroll
        for (int j = 0; j < 4; ++j) {
            uint4 pk;
            pk.x = f2bf2(av[2 * j].x, av[2 * j].y);
            pk.y = f2bf2(av[2 * j].z, av[2 * j].w);
            pk.z = f2bf2(av[2 * j + 1].x, av[2 * j + 1].y);
            pk.w = f2bf2(av[2 * j + 1].z, av[2 * j + 1].w);
            *reinterpret_cast<uint4*>(
                &As[buf][a_base + ((a_half * 4 + j) ^ a_rx) * 8]) = pk;
        }
    };
    auto stageB = [&](int buf, int kt) {
#pragma unroll
        for (int q = 0; q < 4; ++q) {
            const int c = w * 4 + q;
            gload_lds16(Wb2 + (size_t)kt * PANEL + c * 512 + lane * 8,
                        &Bs[buf][c * 512]);
        }
    };
    auto compute = [&](int buf) {
#pragma unroll
        for (int kk = 0; kk < 2; ++kk) {
            const int ks = ((kk * 4 + akk) ^ cx) * 8;
            bf16x8 bq[4];
#pragma unroll
            for (int n = 0; n < 4; ++n)
                bq[n] = *reinterpret_cast<const bf16x8*>(
                    &Bs[buf][(wn * 64 + n * 16 + frow) * 64 + ks]);
#pragma unroll
            for (int mh = 0; mh < 2; ++mh) {
                bf16x8 af[4];
#pragma unroll
                for (int m = 0; m < 4; ++m)
                    af[m] = *reinterpret_cast<const bf16x8*>(
                        &As[buf][(wm * 128 + (mh * 4 + m) * 16 + frow) * 64 + ks]);
                __builtin_amdgcn_s_setprio(1);
#pragma unroll
                for (int m = 0; m < 4; ++m)
#pragma unroll
                    for (int n = 0; n < 4; ++n)
                        acc[mh * 4 + m][n] = __builtin_amdgcn_mfma_f32_16x16x32_bf16(
                            af[m], bq[n], acc[mh * 4 + m][n], 0, 0, 0);
                __builtin_amdgcn_s_setprio(0);
            }
        }
    };

    // ---- prologue: A(0) -> LDS buf0 (one-time drain), B(0) DMA in flight
    loadA(0);
    WAITV(0);
    storeA(0);
    stageB(0, 0);

    // ---- main loop: one barrier per K-tile; staging issued AFTER the barrier
    // (all waves past tile t-1's reads -> WAR-safe), counted vmcnt never 0.
#pragma unroll
    for (int t = 0; t < NTILES; ++t) {
        const int buf = t & 1;
        WAITLGKM;                           // my ds_writes/reads retired
        __builtin_amdgcn_s_barrier();       // all waves done with buf^1
        __builtin_amdgcn_sched_barrier(0);
        if (t < NTILES - 1) {
            loadA(t + 1);                   // queue: B4(t), A8
            stageB(buf ^ 1, t + 1);         // queue: B4(t), A8, B4(t+1)
            WAITV(12);                      // drain B(t); 12 stay in flight
        } else {
            WAITV(0);                       // tail: only B(7) outstanding
        }
        __builtin_amdgcn_sched_barrier(0);
        compute(buf);
        if (t < NTILES - 1) {
            WAITV(4);                       // drain A(t+1); B(t+1) keeps flying
            __builtin_amdgcn_sched_barrier(0);
            storeA(buf ^ 1);
        }
    }

    // ---- epilogue: D mapping col = lane&15, row = (lane>>4)*4 + j
    const float* bn = Bias + node * DOUT + ntile * 256;
    float* outb = Out + (size_t)brow * OUTSTRIDE + node * DOUT + ntile * 256;
#pragma unroll
    for (int n = 0; n < 4; ++n) {
        const int col = wn * 64 + n * 16 + frow;
        const float bias = bn[col];
#pragma unroll
        for (int m = 0; m < 8; ++m) {
            const int r0 = wm * 128 + m * 16 + akk * 4;
#pragma unroll
            for (int j = 0; j < 4; ++j)
                outb[(size_t)(r0 + j) * OUTSTRIDE + col] = acc[m][n][j] + bias;
        }
    }
}

extern "C" void kernel_launch(void* const* d_in, const int* in_sizes, int n_in,
                              void* d_out, int out_size, void* d_ws, size_t ws_size,
                              hipStream_t stream) {
    const float* x = (const float*)d_in[0];      // [2048, 64, 512]
    const float* W = (const float*)d_in[1];      // [64, 512, 512]
    const float* b = (const float*)d_in[2];      // [64, 512]
    float* out = (float*)d_out;                  // [2048, 64*512]
    unsigned short* Wt2 = (unsigned short*)d_ws; // bf16, 33.5 MB, K-tiled+swizzled

    wt_transpose_kernel<<<dim3(DIN / 32, DOUT / 32, NN), dim3(32, 8), 0, stream>>>(W, Wt2);
    node_gemm_kernel<<<dim3(1024), dim3(512), 0, stream>>>(x, Wt2, b, out);
}